// Round 11
// baseline (891.929 us; speedup 1.0000x reference)
//
#include <hip/hip_runtime.h>

#define DCH 384
#define NPROX 64
#define HW 16384          // 128*128
#define NPIX (32 * HW)
#define CHUNK 4

// Fused, zero-workspace kernel.
// Phase 0 (per block, redundant, cheap): proxy inv-norms + pn into LDS.
// Phase 1: 1 pixel/lane, 64 fp32 accumulators over raw-proxy dots;
//          both L2 normalizations folded into the epilogue:
//            dot(x_hat, p_hat) = (x . p) * inv_x * inv_p
//            min_p sqrt(d2_p)  = sqrt(min_p d2_p)   (sqrt monotone)
__global__ __launch_bounds__(256) void fused_min_dist(
        const float* __restrict__ x,
        const float* __restrict__ proxies,
        float* __restrict__ out,
        int nout) {
    __shared__ float partial[256];
    __shared__ float s_inv[NPROX];   // 1/max(||p||, eps)
    __shared__ float s_pn[NPROX];    // ||p_hat||^2 (ref's pn up to fp32 rounding)

    const int t = threadIdx.x;

    // ---- phase 0: proxy norms (256 threads; 4 partial sums per proxy) ----
    {
        const int p = t & 63;
        const int q = t >> 6;                        // 0..3 -> 96 channels each
        const float* pr = proxies + p * DCH + q * 96;
        float s = 0.f;
        for (int i = 0; i < 96; ++i) s = fmaf(pr[i], pr[i], s);
        partial[t] = s;
        __syncthreads();
        if (t < NPROX) {
            float tot = partial[t] + partial[t + 64] + partial[t + 128] + partial[t + 192];
            float inv = 1.0f / fmaxf(sqrtf(tot), 1e-12f);
            s_inv[t] = inv;
            s_pn[t]  = (tot * inv) * inv;
        }
        __syncthreads();
    }

    // ---- phase 1: per-pixel min distance ----
    const int n = blockIdx.x * 256 + t;              // pixel id
    if (n >= NPIX || n >= nout) return;
    const int b  = n >> 14;                          // n / HW
    const int hw = n & (HW - 1);                     // n % HW
    const float* px = x + (size_t)b * (DCH * HW) + hw;

    float acc[NPROX];
#pragma unroll
    for (int p = 0; p < NPROX; ++p) acc[p] = 0.f;
    float ss = 0.f;

    for (int c0 = 0; c0 < DCH; c0 += CHUNK) {
        float xv[CHUNK];
#pragma unroll
        for (int j = 0; j < CHUNK; ++j) xv[j] = px[(size_t)(c0 + j) * HW];  // coalesced
#pragma unroll
        for (int j = 0; j < CHUNK; ++j) ss = fmaf(xv[j], xv[j], ss);

        // Proxy reads: address depends only on (p, c0) -> wave-uniform;
        // float4 keeps issue count low, uniformity analysis may scalarize.
#pragma unroll
        for (int p = 0; p < NPROX; ++p) {
            const float4 pv = *(const float4*)(proxies + p * DCH + c0);
            acc[p] = fmaf(xv[0], pv.x, acc[p]);
            acc[p] = fmaf(xv[1], pv.y, acc[p]);
            acc[p] = fmaf(xv[2], pv.z, acc[p]);
            acc[p] = fmaf(xv[3], pv.w, acc[p]);
        }
    }

    const float invx = 1.0f / fmaxf(sqrtf(ss), 1e-12f);
    const float fn   = (ss * invx) * invx;           // ref's per-pixel fn (~1.0)

    float m = 3.4e38f;
#pragma unroll
    for (int p = 0; p < NPROX; ++p) {
        const float dotn = acc[p] * invx * s_inv[p];
        const float d2   = fn + s_pn[p] - 2.0f * dotn;
        m = fminf(m, d2);
    }
    out[n] = sqrtf(fmaxf(m, 0.0f));
}

extern "C" void kernel_launch(void* const* d_in, const int* in_sizes, int n_in,
                              void* d_out, int out_size, void* d_ws, size_t ws_size,
                              hipStream_t stream) {
    const float* x       = (const float*)d_in[0];   // (32, 384, 128, 128) fp32
    const float* proxies = (const float*)d_in[1];   // (64, 384) fp32
    float* out = (float*)d_out;                     // (32, 128, 128) fp32
    (void)d_ws; (void)ws_size; (void)in_sizes; (void)n_in;

    fused_min_dist<<<(NPIX + 255) / 256, 256, 0, stream>>>(x, proxies, out, out_size);
}